// Round 11
// baseline (245.113 us; speedup 1.0000x reference)
//
#include <hip/hip_runtime.h>
#include <math.h>

#define Bc 4
#define Lc 512
#define Dc 768
#define Hc 12
#define Mc 48
#define Ec 32
#define Pc 512
#define Rc 97
#define MINV 1e-30f
#define NSLICE 12

typedef _Float16 f16;
typedef __attribute__((ext_vector_type(8))) _Float16 f16x8;
typedef __attribute__((ext_vector_type(4))) _Float16 f16x4;
typedef __attribute__((ext_vector_type(16))) float f32x16;

// ---------------- K_prep (critical path only): ctx transpose + mm cvt + em_tok + tmpML zero ----------------
__global__ __launch_bounds__(256) void k_prep(const float* __restrict__ ctx, f16* __restrict__ ctxT,
                                              const float* __restrict__ mm, f16* __restrict__ mmH,
                                              const float* __restrict__ em, f16* __restrict__ emtH,
                                              float* __restrict__ tmpML) {
    __shared__ f16 Ts[64][72];
    __shared__ float rowS[Mc];
    __shared__ float red[256];
    __shared__ float inv;
    int bid = blockIdx.x;
    int tid = threadIdx.x;
    if (bid < 384) {
        int id = bid;                  // ((b*8+lt)*12+dt)
        int dt = id % 12; int lt = (id / 12) % 8; int b = id / 96;
        int l0 = lt * 64, d0 = dt * 64;
        int r = tid >> 2, cg = tid & 3;
        const float* src = ctx + ((size_t)b * Lc + l0 + r) * Dc + d0 + cg * 16;
#pragma unroll
        for (int u = 0; u < 4; ++u) {
            float4 v = ((const float4*)src)[u];
            Ts[cg * 16 + u * 4 + 0][r] = (f16)v.x;
            Ts[cg * 16 + u * 4 + 1][r] = (f16)v.y;
            Ts[cg * 16 + u * 4 + 2][r] = (f16)v.z;
            Ts[cg * 16 + u * 4 + 3][r] = (f16)v.w;
        }
        __syncthreads();
        int dr = tid >> 2, seg = tid & 3;
        f16* dst = ctxT + ((size_t)b * Dc + d0 + dr) * Lc + l0 + seg * 16;
        f16x8 o0, o1;
#pragma unroll
        for (int j = 0; j < 8; ++j) { o0[j] = Ts[dr][seg * 16 + j]; o1[j] = Ts[dr][seg * 16 + 8 + j]; }
        *(f16x8*)dst = o0;
        *(f16x8*)(dst + 8) = o1;
    } else if (bid < 432) {
        // mm -> f16, 8 elems/thread: 48 blocks
        int gid = (bid - 384) * 256 + tid;
        const float4* src = (const float4*)(mm + (size_t)gid * 8);
        float4 v0 = src[0], v1 = src[1];
        f16x8 o;
        o[0] = (f16)v0.x; o[1] = (f16)v0.y; o[2] = (f16)v0.z; o[3] = (f16)v0.w;
        o[4] = (f16)v1.x; o[5] = (f16)v1.y; o[6] = (f16)v1.z; o[7] = (f16)v1.w;
        ((f16x8*)mmH)[gid] = o;
    } else if (bid < 560) {
        // em_tok: 128 blocks, one per (b,e)
        int be = bid - 432; int b = be / Ec;
        if (tid < Mc) rowS[tid] = em[(size_t)be * Mc + tid];
        __syncthreads();
        float v0 = 0.f, v1 = 0.f;
        {
            const float* mb0 = mm + (size_t)b * Mc * Lc + tid;
            const float* mb1 = mm + (size_t)b * Mc * Lc + tid + 256;
            for (int m = 0; m < Mc; ++m) {
                v0 += rowS[m] * mb0[(size_t)m * Lc];
                v1 += rowS[m] * mb1[(size_t)m * Lc];
            }
        }
        red[tid] = v0 + v1;
        __syncthreads();
        for (int s = 128; s > 0; s >>= 1) { if (tid < s) red[tid] += red[tid + s]; __syncthreads(); }
        if (tid == 0) inv = 1.f / (red[0] + MINV);
        __syncthreads();
        emtH[(size_t)be * Lc + tid] = (f16)(v0 * inv);
        emtH[(size_t)be * Lc + tid + 256] = (f16)(v1 * inv);
    } else {
        // tmpML zero
        int base = ((bid - 560) * 256 + tid) * 4;
        float4 z = make_float4(0.f, 0.f, 0.f, 0.f);
        float4* t4 = (float4*)tmpML;
#pragma unroll
        for (int u = 0; u < 4; ++u) t4[base + u] = z;
    }
}

// ---------------- K2 merged: attpass 32-col tiles (0..767) + mention MFMA (768..815)
//                 + weight cvt (816..2863) + clasW->Wp swizzle (2864..5935). ----------------
__global__ __launch_bounds__(256) void k_att_mention(const f16* __restrict__ mmH,
                                                     const f16* __restrict__ emtH,
                                                     const float* __restrict__ att,
                                                     float* __restrict__ tmpML,
                                                     float* __restrict__ eat,
                                                     const f16* __restrict__ ctxT,
                                                     float* __restrict__ mention,
                                                     const float* __restrict__ hW, const float* __restrict__ tW,
                                                     const float* __restrict__ hcW, const float* __restrict__ tcW,
                                                     f16* __restrict__ hWb, f16* __restrict__ tWb,
                                                     f16* __restrict__ hcWb, f16* __restrict__ tcWb,
                                                     const float* __restrict__ clasW, f16* __restrict__ Wp) {
    __shared__ __align__(16) char smem[32768];
    int bid = blockIdx.x;
    int tid = threadIdx.x;
    int w = tid >> 6, lane = tid & 63;
    if (bid < 768) {
        // ---- attpass: 32-col output tile per block (2x parallelism vs 64-col) ----
        f16* Ss   = (f16*)smem;            // 96*64
        f16* attS = (f16*)(smem + 12288);  // 32*64
        int mt = bid & 15; int bh = bid >> 4;
        int b = bh / Hc, h = bh % Hc;
        int m0 = mt * 32;
        int n_l = lane & 31, kg = lane >> 5;

        const float* ab = att + (size_t)bh * Lc * Lc + m0;
        int mRow = tid & 31, lg = tid >> 5;   // col, l-chunk (0..7)
        float pre[8];
#pragma unroll
        for (int q = 0; q < 8; ++q) pre[q] = ab[(size_t)(lg * 8 + q) * Lc + mRow];

        f32x16 acc;
#pragma unroll
        for (int i = 0; i < 16; ++i) acc[i] = 0.f;

        for (int kc = 0; kc < 8; ++kc) {
            __syncthreads();
            {
                f16x8 v;
#pragma unroll
                for (int jj = 0; jj < 8; ++jj) v[jj] = (f16)pre[jj];
                ((f16x8*)attS)[mRow * 8 + (lg ^ (mRow & 7))] = v;
            }
#pragma unroll
            for (int k = 0; k < 3; ++k) {
                int idx = tid + k * 256;
                int row = idx >> 3, cc = idx & 7;
                f16x8 v;
                if (row < Mc) {
                    v = *(const f16x8*)(mmH + ((size_t)b * Mc + row) * Lc + kc * 64 + cc * 8);
                } else if (row < 80) {
                    v = *(const f16x8*)(emtH + ((size_t)b * Ec + row - Mc) * Lc + kc * 64 + cc * 8);
                } else {
#pragma unroll
                    for (int j = 0; j < 8; ++j) v[j] = (f16)0.f;
                }
                ((f16x8*)Ss)[row * 8 + (cc ^ (row & 7))] = v;
            }
            if (kc < 7) {
#pragma unroll
                for (int q = 0; q < 8; ++q)
                    pre[q] = ab[(size_t)((kc + 1) * 64 + lg * 8 + q) * Lc + mRow];
            }
            __syncthreads();
            if (w < 3) {
                int arow = w * 32 + n_l;
#pragma unroll
                for (int kk = 0; kk < 4; ++kk) {
                    int cc = kk * 2 + kg;
                    f16x8 a = ((const f16x8*)Ss)[arow * 8 + (cc ^ (arow & 7))];
                    f16x8 bb = ((const f16x8*)attS)[n_l * 8 + (cc ^ (n_l & 7))];
                    acc = __builtin_amdgcn_mfma_f32_32x32x16_f16(a, bb, acc, 0, 0, 0);
                }
            }
        }
        if (w < 3) {
#pragma unroll
            for (int reg = 0; reg < 16; ++reg) {
                int row = (reg & 3) + 8 * (reg >> 2) + 4 * kg;
                int rr = w * 32 + row;
                int col = m0 + n_l;
                if (rr < Mc) {
                    atomicAdd(&tmpML[((size_t)b * Mc + rr) * Lc + col], acc[reg]);
                } else if (rr < 80) {
                    eat[(((size_t)b * Hc + h) * Ec + (rr - Mc)) * Lc + col] = acc[reg];
                }
            }
        }
    } else if (bid < 816) {
        // ---- mention = mm @ ctx ----
        f16* As = (f16*)smem;             // 2 * 64*64
        f16* Bs = (f16*)(smem + 16384);   // 2 * 64*64
        int id = bid - 768;               // b*12+dt
        int dt = id % 12; int b = id / 12;
        int d0 = dt * 64;
        int w_m = w & 1, w_n = w >> 1;
        int m_l = lane & 31, kg = lane >> 5;
        int r0 = tid >> 3, cc0 = tid & 7;
        int r1 = r0 + 32;
        int mr0 = (r0 < Mc) ? r0 : r0 - Mc;
        int mr1 = (r1 < Mc) ? r1 : r1 - Mc;
        f16x8 ar0, ar1, br0, br1;
        auto loadt = [&](int it) {
            int k0 = it * 64;
            ar0 = *(const f16x8*)(mmH + ((size_t)b * Mc + mr0) * Lc + k0 + cc0 * 8);
            ar1 = *(const f16x8*)(mmH + ((size_t)b * Mc + mr1) * Lc + k0 + cc0 * 8);
            br0 = *(const f16x8*)(ctxT + ((size_t)b * Dc + d0 + r0) * Lc + k0 + cc0 * 8);
            br1 = *(const f16x8*)(ctxT + ((size_t)b * Dc + d0 + r1) * Lc + k0 + cc0 * 8);
        };
        auto writet = [&](int p) {
            ((f16x8*)(As + p * 4096))[r0 * 8 + (cc0 ^ (r0 & 7))] = ar0;
            ((f16x8*)(As + p * 4096))[r1 * 8 + (cc0 ^ (r1 & 7))] = ar1;
            ((f16x8*)(Bs + p * 4096))[r0 * 8 + (cc0 ^ (r0 & 7))] = br0;
            ((f16x8*)(Bs + p * 4096))[r1 * 8 + (cc0 ^ (r1 & 7))] = br1;
        };
        loadt(0); writet(0); loadt(1);
        f32x16 acc;
#pragma unroll
        for (int i = 0; i < 16; ++i) acc[i] = 0.f;
        int ar = w_m * 32 + m_l;
        int br = w_n * 32 + m_l;
        for (int it = 0; it < 8; ++it) {
            int p = it & 1;
            __syncthreads();
            if (it < 7) writet(p ^ 1);
            if (it < 6) loadt(it + 2);
#pragma unroll
            for (int s = 0; s < 4; ++s) {
                int ck = s * 2 + kg;
                f16x8 a = ((const f16x8*)(As + p * 4096))[ar * 8 + (ck ^ (ar & 7))];
                f16x8 bv = ((const f16x8*)(Bs + p * 4096))[br * 8 + (ck ^ (br & 7))];
                acc = __builtin_amdgcn_mfma_f32_32x32x16_f16(a, bv, acc, 0, 0, 0);
            }
        }
#pragma unroll
        for (int reg = 0; reg < 16; ++reg) {
            int row = (reg & 3) + 8 * (reg >> 2) + 4 * kg;
            int m = w_m * 32 + row;
            if (m < Mc) mention[((size_t)b * Mc + m) * Dc + d0 + w_n * 32 + m_l] = acc[reg];
        }
    } else if (bid < 2864) {
        // ---- weight cvt, float4-vectorized ----
        const int Q = 147456;   // DD/4
        int i = (bid - 816) * 256 + tid;
        int stride = 2048 * 256;
        for (; i < 4 * Q; i += stride) {
            int sel = i / Q, j = i % Q;
            const float* s = (sel == 0) ? hW : (sel == 1) ? tW : (sel == 2) ? hcW : tcW;
            f16* d = (sel == 0) ? hWb : (sel == 1) ? tWb : (sel == 2) ? hcWb : tcWb;
            float4 v = ((const float4*)s)[j];
            f16x4 o;
            o[0] = (f16)v.x; o[1] = (f16)v.y; o[2] = (f16)v.z; o[3] = (f16)v.w;
            ((f16x4*)d)[j] = o;
        }
    } else {
        // ---- clasW -> Wp swizzle, LDS-staged ----
        f16 (*LsW)[72] = (f16 (*)[72])smem;
        int id2 = bid - 2864;
        int c = id2 >> 2, rt = id2 & 3;
        for (int idx = tid; idx < 512; idx += 256) {
            int row = idx >> 4, q = idx & 15;
            int r = rt * 32 + row;
            f16x4 o;
            if (r < Rc) {
                float4 v = *(const float4*)(clasW + (size_t)r * (Dc * 64) + c * 64 + q * 4);
                o[0] = (f16)v.x; o[1] = (f16)v.y; o[2] = (f16)v.z; o[3] = (f16)v.w;
            } else {
                o[0] = (f16)0.f; o[1] = (f16)0.f; o[2] = (f16)0.f; o[3] = (f16)0.f;
            }
            *(f16x4*)(&LsW[row][q * 4]) = o;
        }
        __syncthreads();
        int s = tid >> 6;
        int n_l = lane & 31, kg = lane >> 5;
        f16x8 outv = *(const f16x8*)(&LsW[n_l][s * 16 + kg * 8]);
        ((f16x8*)Wp)[(size_t)(c * 16 + s * 4 + rt) * 64 + lane] = outv;
    }
}

// ---------------- K3a: mention_att, one wave per output element (fp32) ----------------
__global__ __launch_bounds__(256) void k_ma(const float* __restrict__ tmp,
                                            const float* __restrict__ mm,
                                            float* __restrict__ maS) {
    int wv = threadIdx.x >> 6, lane = threadIdx.x & 63;
    int gid = blockIdx.x * 4 + wv;              // < Bc*48*48 = 9216
    int m2 = gid % 48;
    int m  = (gid / 48) % 48;
    int b  = gid / (48 * 48);
    const float4* t = (const float4*)(tmp + ((size_t)b * Mc + m)  * Lc);
    const float4* r = (const float4*)(mm  + ((size_t)b * Mc + m2) * Lc);
    float4 a0 = t[lane],      b0 = r[lane];
    float4 a1 = t[lane + 64], b1 = r[lane + 64];
    float acc = a0.x * b0.x + a0.y * b0.y + a0.z * b0.z + a0.w * b0.w
              + a1.x * b1.x + a1.y * b1.y + a1.z * b1.z + a1.w * b1.w;
#pragma unroll
    for (int off = 1; off < 64; off <<= 1) acc += __shfl_xor(acc, off);
    if (lane == 0) maS[gid] = acc;
}

// ---------------- K5a: per-bp pair prep (1 wave per bp), entity_att rows computed inline ----------------
__global__ __launch_bounds__(256) void k_pair(const int* __restrict__ hts,
                                              const float* __restrict__ em,
                                              const float* __restrict__ maS,
                                              const float* __restrict__ eat,
                                              f16* __restrict__ hatN, f16* __restrict__ tatN,
                                              f16* __restrict__ caH) {
    int wv = threadIdx.x >> 6, lane = threadIdx.x & 63;
    int bp = blockIdx.x * 4 + wv;
    int b = bp >> 9;
    int hi = hts[bp * 2], ti = hts[bp * 2 + 1];
    float mask = (hi + ti != 0) ? 1.f : 0.f;
    float hat = 0.f, tat = 0.f;
    if (lane < Mc) {
        float hm = em[((size_t)(b * Ec + hi)) * Mc + lane];
        float tm = em[((size_t)(b * Ec + ti)) * Mc + lane];
        float eh = 0.f, et = 0.f;
        const float* maB = maS + (size_t)b * Mc * Mc;
        const float* emH = em + ((size_t)(b * Ec + hi)) * Mc;
        const float* emT = em + ((size_t)(b * Ec + ti)) * Mc;
#pragma unroll 8
        for (int m = 0; m < Mc; ++m) {
            float ms = maB[m * Mc + lane];
            eh += emH[m] * ms;
            et += emT[m] * ms;
        }
        hat = eh * tm * mask;
        tat = et * hm * mask;
    }
    float sh = hat, st = tat;
#pragma unroll
    for (int off = 1; off < 64; off <<= 1) { sh += __shfl_xor(sh, off); st += __shfl_xor(st, off); }
    float hnorm = 1.f / (sh + MINV);
    float tnorm = 1.f / (st + MINV);
    hatN[(size_t)bp * 64 + lane] = (f16)(hat * hnorm);
    tatN[(size_t)bp * 64 + lane] = (f16)(tat * tnorm);

    const float* base = eat + (size_t)b * Hc * Ec * Lc;
    float prod[8];
    float tot = 0.f;
#pragma unroll
    for (int j8 = 0; j8 < 8; ++j8) {
        int j = j8 * 64 + lane;
        float a = 0.f;
#pragma unroll
        for (int h = 0; h < Hc; ++h)
            a += base[((size_t)h * Ec + hi) * Lc + j] * base[((size_t)h * Ec + ti) * Lc + j];
        prod[j8] = a;
        tot += a;
    }
#pragma unroll
    for (int off = 1; off < 64; off <<= 1) tot += __shfl_xor(tot, off);
    float inv = 1.f / (tot + MINV);
#pragma unroll
    for (int j8 = 0; j8 < 8; ++j8)
        caH[(size_t)bp * Lc + j8 * 64 + lane] = (f16)(prod[j8] * inv);
}

// ---------------- K5b merged: ht MFMA (blocks 0..383) + ctxinfo MFMA (blocks 384..767) ----------------
__global__ __launch_bounds__(256) void k_htci(const f16* __restrict__ tatN, const f16* __restrict__ hatN,
                                              const float* __restrict__ mention,
                                              f16* __restrict__ hB, f16* __restrict__ tB,
                                              const int* __restrict__ hts,
                                              const f16* __restrict__ caH,
                                              const f16* __restrict__ ctxT,
                                              f16* __restrict__ ci) {
    __shared__ __align__(16) char smem[33024];
    int bid = blockIdx.x;
    int tid = threadIdx.x;
    int w = tid >> 6, lane = tid & 63;
    int w_m = w & 1, w_n = w >> 1;
    int m_l = lane & 31, kg = lane >> 5;
    if (bid < 384) {
        // ---- ht: h = tatN @ mention, t = hatN @ mention (K=64 single tile) ----
        f16* At = (f16*)smem;              // 64*64
        f16* Ah = (f16*)(smem + 8192);     // 64*64
        f16* Bs = (f16*)(smem + 16384);    // 64*64
        int m0 = (bid & 31) * 64;          // p base
        int b = m0 >> 9;
        int d0 = (bid >> 5) * 64;

        for (int i = tid; i < 512; i += 256) {
            int p = i >> 3, c = i & 7;
            ((f16x8*)At)[p * 8 + (c ^ (p & 7))] = *(const f16x8*)(tatN + (size_t)(m0 + p) * 64 + c * 8);
            ((f16x8*)Ah)[p * 8 + (c ^ (p & 7))] = *(const f16x8*)(hatN + (size_t)(m0 + p) * 64 + c * 8);
        }
        for (int i = tid; i < 512; i += 256) {
            f16x8 z;
#pragma unroll
            for (int j = 0; j < 8; ++j) z[j] = (f16)0.f;
            ((f16x8*)Bs)[i] = z;
        }
        __syncthreads();
        if (tid < 192) {
            int m = tid >> 2, q = tid & 3;
            const float4* src = (const float4*)(mention + ((size_t)b * Mc + m) * Dc + d0 + q * 16);
#pragma unroll
            for (int u = 0; u < 4; ++u) {
                float4 v = src[u];
                int dl = q * 16 + u * 4;
#pragma unroll
                for (int x = 0; x < 4; ++x) {
                    float vv = (x == 0) ? v.x : (x == 1) ? v.y : (x == 2) ? v.z : v.w;
                    int d = dl + x;
                    Bs[(d * 8 + ((m >> 3) ^ (d & 7))) * 8 + (m & 7)] = (f16)vv;
                }
            }
        }
        __syncthreads();

        f32x16 acch, acct;
#pragma unroll
        for (int i = 0; i < 16; ++i) { acch[i] = 0.f; acct[i] = 0.f; }
        int ar = w_m * 32 + m_l;
        int br = w_n * 32 + m_l;
#pragma unroll
        for (int s = 0; s < 4; ++s) {
            int ck = s * 2 + kg;
            f16x8 at_ = ((const f16x8*)At)[ar * 8 + (ck ^ (ar & 7))];
            f16x8 ah_ = ((const f16x8*)Ah)[ar * 8 + (ck ^ (ar & 7))];
            f16x8 bv = ((const f16x8*)Bs)[br * 8 + (ck ^ (br & 7))];
            acch = __builtin_amdgcn_mfma_f32_32x32x16_f16(at_, bv, acch, 0, 0, 0);
            acct = __builtin_amdgcn_mfma_f32_32x32x16_f16(ah_, bv, acct, 0, 0, 0);
        }
#pragma unroll
        for (int reg = 0; reg < 16; ++reg) {
            int row = (reg & 3) + 8 * (reg >> 2) + 4 * kg;
            int p = m0 + w_m * 32 + row;
            int d = d0 + w_n * 32 + m_l;
            hB[(size_t)p * Dc + d] = (f16)acch[reg];
            tB[(size_t)p * Dc + d] = (f16)acct[reg];
        }
    } else {
        // ---- ctxinfo = ca @ ctx^T, masked ----
        f16* As = (f16*)smem;              // 2 * 64*64
        f16* Bs = (f16*)(smem + 16384);    // 2 * 64*64
        float* maskS = (float*)(smem + 32768);
        int id = bid - 384;                // ((b*8+pt)*12+dt)
        int dt = id % 12; int pt = (id / 12) % 8; int b = id / 96;
        int p0 = pt * 64, d0 = dt * 64;
        int r0 = tid >> 3, cc0 = tid & 7;
        int r1 = r0 + 32;
        if (tid < 64) {
            int bp = b * Pc + p0 + tid;
            maskS[tid] = (hts[bp * 2] + hts[bp * 2 + 1] != 0) ? 1.f : 0.f;
        }
        f16x8 ar0, ar1, br0, br1;
        auto loadt = [&](int it) {
            int k0 = it * 64;
            ar0 = *(const f16x8*)(caH + (size_t)(b * Pc + p0 + r0) * Lc + k0 + cc0 * 8);
            ar1 = *(const f16x8*)(caH + (size_t)(b * Pc + p0 + r1) * Lc + k0 + cc0 * 8);
            br0 = *(const f16x8*)(ctxT + (size_t)(b * Dc + d0 + r0) * Lc + k0 + cc0 * 8);
            br1 = *(const f16x8*)(ctxT + (size_t)(b * Dc + d0 + r1) * Lc + k0 + cc0 * 8);
        };
        auto writet = [&](int p) {
            ((f16x8*)(As + p * 4096))[r0 * 8 + (cc0 ^ (r0 & 7))] = ar0;
            ((f16x8*)(As + p * 4096))[r1 * 8 + (cc0 ^ (r1 & 7))] = ar1;
            ((f16x8*)(Bs + p * 4096))[r0 * 8 + (cc0 ^ (r0 & 7))] = br0;
            ((f16x8*)(Bs + p * 4096))[r1 * 8 + (cc0 ^ (r1 & 7))] = br1;
        };
        loadt(0); writet(0); loadt(1);
        f32x16 acc;
#pragma unroll
        for (int i = 0; i < 16; ++i) acc[i] = 0.f;
        int ar = w_m * 32 + m_l;
        int br = w_n * 32 + m_l;
        for (int it = 0; it < 8; ++it) {
            int p = it & 1;
            __syncthreads();
            if (it < 7) writet(p ^ 1);
            if (it < 6) loadt(it + 2);
#pragma unroll
            for (int s = 0; s < 4; ++s) {
                int ck = s * 2 + kg;
                f16x8 a = ((const f16x8*)(As + p * 4096))[ar * 8 + (ck ^ (ar & 7))];
                f16x8 bv = ((const f16x8*)(Bs + p * 4096))[br * 8 + (ck ^ (br & 7))];
                acc = __builtin_amdgcn_mfma_f32_32x32x16_f16(a, bv, acc, 0, 0, 0);
            }
        }
#pragma unroll
        for (int reg = 0; reg < 16; ++reg) {
            int row = (reg & 3) + 8 * (reg >> 2) + 4 * kg;
            int p = p0 + w_m * 32 + row;
            int d = d0 + w_n * 32 + m_l;
            ci[(size_t)(b * Pc + p) * Dc + d] = (f16)(acc[reg] * maskS[w_m * 32 + row]);
        }
    }
}

// ---------------- K10: MFMA proj merged (z=2), f16, global_load_lds staging ----------------
__global__ __launch_bounds__(256) void k_proj_mfma(const f16* __restrict__ Xh, const f16* __restrict__ Wh,
                                                   const float* __restrict__ bh,
                                                   const f16* __restrict__ Xt, const f16* __restrict__ Wt,
                                                   const float* __restrict__ bt,
                                                   const f16* __restrict__ Xc, const f16* __restrict__ Whc,
                                                   const float* __restrict__ bhc,
                                                   const f16* __restrict__ Wtc, const float* __restrict__ btc,
                                                   f16* __restrict__ outh, f16* __restrict__ outt) {
    __shared__ __align__(16) f16 Xs[2][64 * 64];
    __shared__ __align__(16) f16 Ws[2][64 * 64];
    int z = blockIdx.z;
    const f16* X1 = z ? Xt : Xh;
    const f16* W1 = z ? Wt : Wh;
    const float* b1 = z ? bt : bh;
    const f16* W2 = z ? Wtc : Whc;
    const float* b2 = z ? btc : bhc;
    f16* outp = z ? outt : outh;
    int m0 = blockIdx.x * 64, n0 = blockIdx.y * 64;
    int tid = threadIdx.x;
    int w = tid >> 6, lane = tid & 63;
    int w_m = w & 1, w_n = w >> 1;
    int m_l = lane & 31, kg = lane >> 5;
    const f16* Xarr[2] = {X1, Xc};
    const f16* Warr[2] = {W1, W2};

    auto stage = [&](int p, int it) {
        int src = it / 12; int k0 = (it % 12) * 64;
        const f16* X = Xarr[src]; const f16* W = Warr[src];
#pragma unroll
        for (int g = 0; g < 2; ++g) {
            int s = g * 256 + w * 64 + lane;
            int r = s >> 3, c = (s & 7) ^ (r & 7);
            __builtin_amdgcn_global_load_lds(
                (const __attribute__((address_space(1))) void*)(X + (size_t)(m0 + r) * Dc + k0 + c * 8),
                (__attribute__((address_space(3))) void*)(&Xs[p][(g * 256 + w * 64) * 8]),
                16, 0, 0);
            __builtin_amdgcn_global_load_lds(
                (const __attribute__((address_space(1))) void*)(W + (size_t)(n0 + r) * Dc + k0 + c * 8),
                (__attribute__((address_space(3))) void*)(&Ws[p][(g * 256 + w * 64) * 8]),
                16, 0, 0);
        }
    };

    stage(0, 0);
    f32x16 acc;
#pragma unroll
    for (int i = 0; i < 16; ++i) acc[i] = 0.f;
    int ar = w_m * 32 + m_l;
    int br = w_n * 32 + m_l;
    for (int it = 0; it < 24; ++it) {
        int p = it & 1;
        __syncthreads();
        if (it < 23) stage(p ^ 1, it + 1);
#pragma unroll
        for (int s = 0; s < 4; ++s) {
            int ck = s * 2 + kg;
            f16x8 a = ((const f16x8*)Xs[p])[ar * 8 + (ck ^ (ar & 7))];
            f16x8 b = ((const f16x8*)Ws[p])[br * 8 + (ck ^ (br & 7))];
            acc = __builtin_amdgcn_mfma_f32_32x32x16_f16(a, b, acc, 0, 0, 0);
        }
    }
#pragma unroll
    for (int reg = 0; reg < 16; ++reg) {
        int row = (reg & 3) + 8 * (reg >> 2) + 4 * kg;
        int m = m0 + w_m * 32 + row;
        int n = n0 + w_n * 32 + m_l;
        float v = tanhf(acc[reg] + b1[n] + b2[n]);
        outp[(size_t)m * Dc + n] = (f16)v;
    }
}

// ---------------- K11: group bilinear. tile=128 bp, slice=64 cc (one n-group), rt per block. ----------------
__global__ __launch_bounds__(256, 3) void k_bilin(const f16* __restrict__ hF, const f16* __restrict__ tF,
                                                  const f16* __restrict__ Wp, f16* __restrict__ partial) {
    __shared__ __align__(16) f16 tS[128 * 64];   // reused as f32 combine buffer after the cc loop
    __shared__ f16 hS[128 * 65];
    int id = blockIdx.x;
    int rt = id & 3;               // r-tile 0..3
    int st = id >> 2;
    int slice = st % NSLICE;       // 12 slices of 64 cc = one n-group each
    int tile = st / NSLICE;        // 16 tiles of 128 bp
    int bp0 = tile * 128;
    int c0 = slice * 64;
    int n = slice;
    int tid = threadIdx.x;
    int w = tid >> 6, lane = tid & 63;
    int w_m = w & 1, w_half = w >> 1;   // cc half (0: cc 0..31, 1: cc 32..63)
    int m_l = lane & 31, kg = lane >> 5;

    for (int idx = tid; idx < 128 * 8; idx += 256) {
        int bp = idx >> 3, seg = idx & 7;
        f16x8 hv = *(const f16x8*)(hF + (size_t)(bp0 + bp) * Dc + c0 + seg * 8);
#pragma unroll
        for (int j = 0; j < 8; ++j) hS[bp * 65 + seg * 8 + j] = hv[j];
    }
    for (int idx = tid; idx < 128 * 8; idx += 256) {
        int bp = idx >> 3, cc = idx & 7;
        f16x8 tv = *(const f16x8*)(tF + (size_t)(bp0 + bp) * Dc + n * 64 + cc * 8);
        ((f16x8*)tS)[bp * 8 + (cc ^ (bp & 7))] = tv;
    }
    __syncthreads();

    int rowA = w_m * 64 + m_l;
    int rowB = rowA + 32;

    f16x8 tvA[4], tvB[4];
#pragma unroll
    for (int s = 0; s < 4; ++s) {
        int ck = s * 2 + kg;
        tvA[s] = ((const f16x8*)tS)[rowA * 8 + (ck ^ (rowA & 7))];
        tvB[s] = ((const f16x8*)tS)[rowB * 8 + (ck ^ (rowB & 7))];
    }

    f32x16 acc[2];
#pragma unroll
    for (int mt = 0; mt < 2; ++mt)
#pragma unroll
        for (int i = 0; i < 16; ++i) acc[mt][i] = 0.f;

    const f16x8* wpb = (const f16x8*)Wp + ((size_t)(c0 + w_half * 32) * 16 + rt) * 64 + lane;
    int hbase = w_half * 32;
    f16x8 BfA[4], BfB[4];
#pragma unroll
    for (int s = 0; s < 4; ++s) BfA[s] = wpb[s * 256];

    for (int io = 0; io < 32; io += 2) {
#pragma unroll
        for (int s = 0; s < 4; ++s) BfB[s] = wpb[(io + 1) * 1024 + s * 256];
        {
            f16 hv0 = hS[rowA * 65 + hbase + io];
            f16 hv1 = hS[rowB * 65 + hbase + io];
#pragma unroll
            for (int s = 0; s < 4; ++s) {
                f16x8 a0 = tvA[s] * hv0;
                f16x8 a1 = tvB[s] * hv1;
                acc[0] = __builtin_amdgcn_mfma_f32_32x32x16_f16(a0, BfA[s], acc[0], 0, 0, 0);
                acc[1] = __builtin_amdgcn_mfma_f32_32x32x16_f16(a1, BfA[s], acc[1], 0, 0, 0);
            }
        }
        if (io + 2 < 32) {
#pragma unroll
            for (int s = 0; s < 4; ++s) BfA[s] = wpb[(io + 2) * 1024 + s * 256];
        }
        {
            f16 hv0 = hS[rowA * 65 + hbase + io + 1];
            f16 hv1 = hS[rowB * 65 + hbase + io + 1];
#pragma unroll
            for (int s = 0; s < 4; ++s) {
                f16x8 a0 = tvA[s] * hv0;
                f16x8 a1 = tvB[s] * hv1;
                acc[0] = __builtin_amdgcn_mfma_f32_32x32x16_f16(a0, BfB[s], acc[0], 0, 0, 0);
                acc[1] = __builtin_amdgcn_mfma_f32_32x32x16_f16(a1, BfB[s], acc[1], 0, 0, 0);
            }
        }
    }

    float* comb = (float*)tS;    // 4*16*64 f32 = 16 KB
    __syncthreads();
    if (w_half == 1) {
#pragma unroll
        for (int mt = 0; mt < 2; ++mt)
#pragma unroll
            for (int reg = 0; reg < 16; ++reg)
                comb[((w_m * 2 + mt) * 16 + reg) * 64 + lane] = acc[mt][reg];
    }
    __syncthreads();
    if (w_half == 0) {
        f16* pbase = partial + (size_t)slice * (2048 * 128);
        int r = rt * 32 + m_l;
#pragma unroll
        for (int mt = 0; mt < 2; ++mt)
#pragma unroll
            for (int reg = 0; reg < 16; ++reg) {
                float v = acc[mt][reg] + comb[((w_m * 2 + mt) * 16 + reg) * 64 + lane];
                int row = (reg & 3) + 8 * (reg >> 2) + 4 * kg;
                int bp = bp0 + w_m * 64 + mt * 32 + row;
                pbase[(size_t)bp * 128 + r] = (f16)v;
            }
    }
}

// ---------------- K12: reduce partials + bias -> out ----------------
__global__ __launch_bounds__(256) void k_reduce(const f16* __restrict__ partial,
                                                const float* __restrict__ cb,
                                                float* __restrict__ out) {
    int idx = blockIdx.x * 256 + threadIdx.x;   // < 2048*32 (f16x4 chunks)
    int bp = idx >> 5, c = idx & 31;
    const f16x4* p = (const f16x4*)partial + idx;
    float a0 = 0.f, a1 = 0.f, a2 = 0.f, a3 = 0.f;
#pragma unroll
    for (int s = 0; s < NSLICE; ++s) {
        f16x4 v = p[(size_t)s * (2048 * 32)];
        a0 += (float)v[0]; a1 += (float)v[1]; a2 += (float)v[2]; a3 += (float)v[3];
    }
    int rb = c * 4;
    float* ob = out + (size_t)bp * Rc;
    if (rb + 0 < Rc) ob[rb + 0] = a0 + cb[rb + 0];
    if (rb + 1 < Rc) ob[rb + 1] = a1 + cb[rb + 1];
    if (rb + 2 < Rc) ob[rb + 2] = a2 + cb[rb + 2];
    if (rb + 3 < Rc) ob[rb + 3] = a3 + cb[rb + 3];
}

extern "C" void kernel_launch(void* const* d_in, const int* in_sizes, int n_in,
                              void* d_out, int out_size, void* d_ws, size_t ws_size,
                              hipStream_t stream) {
    const float* context   = (const float*)d_in[0];
    const float* attention = (const float*)d_in[1];
    const float* mm        = (const float*)d_in[2];
    const float* em        = (const float*)d_in[3];
    const int*   hts       = (const int*)d_in[4];
    const float* hW        = (const float*)d_in[5];
    const float* hb        = (const float*)d_in[6];
    const float* tW        = (const float*)d_in[7];
    const float* tb        = (const float*)d_in[8];
    const float* hcW       = (const float*)d_in[9];
    const float* hcb       = (const float*)d_in[10];
    const float* tcW       = (const float*)d_in[11];
    const float* tcb       = (const float*)d_in[12];
    const float* clasW     = (const float*)d_in[13];
    const float* clasb     = (const float*)d_in[14];
    float* out = (float*)d_out;

    char* wsb = (char*)d_ws;
    auto alloc = [&](size_t bytes) { char* p = wsb; wsb += (bytes + 255) & ~(size_t)255; return p; };
    float* mention     = (float*)alloc((size_t)Bc * Mc * Dc * 4);
    float* tmpML       = (float*)alloc((size_t)Bc * Mc * Lc * 4);
    float* ent_att     = (float*)alloc((size_t)Bc * Hc * Ec * Lc * 4);
    float* maS         = (float*)alloc((size_t)Bc * Mc * Mc * 4);
    f16* em_tok  = (f16*)alloc((size_t)Bc * Ec * Lc * 2);
    f16* ctx_att = (f16*)alloc((size_t)Bc * Pc * Lc * 2);
    f16* mmH     = (f16*)alloc((size_t)Bc * Mc * Lc * 2);
    f16* hatN    = (f16*)alloc((size_t)Bc * Pc * 64 * 2);
    f16* tatN    = (f16*)alloc((size_t)Bc * Pc * 64 * 2);
    f16* h_buf   = (f16*)alloc((size_t)Bc * Pc * Dc * 2);
    f16* t_buf   = (f16*)alloc((size_t)Bc * Pc * Dc * 2);
    f16* ctxinfo = (f16*)alloc((size_t)Bc * Pc * Dc * 2);
    f16* h_fin   = (f16*)alloc((size_t)Bc * Pc * Dc * 2);
    f16* t_fin   = (f16*)alloc((size_t)Bc * Pc * Dc * 2);
    f16* hWb     = (f16*)alloc((size_t)Dc * Dc * 2);
    f16* tWb     = (f16*)alloc((size_t)Dc * Dc * 2);
    f16* hcWb    = (f16*)alloc((size_t)Dc * Dc * 2);
    f16* tcWb    = (f16*)alloc((size_t)Dc * Dc * 2);
    f16* ctxT    = (f16*)alloc((size_t)Bc * Dc * Lc * 2);
    f16* Wp      = (f16*)alloc((size_t)768 * 16 * 64 * 8 * 2);
    f16* partial = (f16*)alloc((size_t)NSLICE * 2048 * 128 * 2);

    k_prep<<<dim3(584), dim3(256), 0, stream>>>(context, ctxT, mm, mmH, em, em_tok, tmpML);
    k_att_mention<<<dim3(5936), dim3(256), 0, stream>>>(mmH, em_tok, attention, tmpML, ent_att,
                                                        ctxT, mention,
                                                        hW, tW, hcW, tcW, hWb, tWb, hcWb, tcWb,
                                                        clasW, Wp);
    k_ma<<<dim3(Bc * Mc * Mc / 4), dim3(256), 0, stream>>>(tmpML, mm, maS);
    k_pair<<<dim3(Bc * Pc / 4), dim3(256), 0, stream>>>(hts, em, maS, ent_att, hatN, tatN, ctx_att);
    k_htci<<<dim3(768), dim3(256), 0, stream>>>(tatN, hatN, mention, h_buf, t_buf,
                                                hts, ctx_att, ctxT, ctxinfo);
    k_proj_mfma<<<dim3(32, 12, 2), dim3(256), 0, stream>>>(h_buf, hWb, hb, t_buf, tWb, tb,
                                                           ctxinfo, hcWb, hcb, tcWb, tcb, h_fin, t_fin);
    k_bilin<<<dim3(16 * NSLICE * 4), dim3(256), 0, stream>>>(h_fin, t_fin, Wp, partial);
    k_reduce<<<dim3(256), dim3(256), 0, stream>>>(partial, clasb, out);
}

// Round 12
// 241.030 us; speedup vs baseline: 1.0169x; 1.0169x over previous
//
#include <hip/hip_runtime.h>
#include <math.h>

#define Bc 4
#define Lc 512
#define Dc 768
#define Hc 12
#define Mc 48
#define Ec 32
#define Pc 512
#define Rc 97
#define MINV 1e-30f
#define NSLICE 12

typedef _Float16 f16;
typedef __attribute__((ext_vector_type(8))) _Float16 f16x8;
typedef __attribute__((ext_vector_type(4))) _Float16 f16x4;
typedef __attribute__((ext_vector_type(16))) float f32x16;

// ---------------- K_prep: ctx transpose + mm cvt + em_tok + tmpML zero + out bias init ----------------
__global__ __launch_bounds__(256) void k_prep(const float* __restrict__ ctx, f16* __restrict__ ctxT,
                                              const float* __restrict__ mm, f16* __restrict__ mmH,
                                              const float* __restrict__ em, f16* __restrict__ emtH,
                                              float* __restrict__ tmpML,
                                              const float* __restrict__ cb, float* __restrict__ out) {
    __shared__ f16 Ts[64][72];
    __shared__ float rowS[Mc];
    __shared__ float red[256];
    __shared__ float inv;
    int bid = blockIdx.x;
    int tid = threadIdx.x;
    if (bid < 384) {
        int id = bid;                  // ((b*8+lt)*12+dt)
        int dt = id % 12; int lt = (id / 12) % 8; int b = id / 96;
        int l0 = lt * 64, d0 = dt * 64;
        int r = tid >> 2, cg = tid & 3;
        const float* src = ctx + ((size_t)b * Lc + l0 + r) * Dc + d0 + cg * 16;
#pragma unroll
        for (int u = 0; u < 4; ++u) {
            float4 v = ((const float4*)src)[u];
            Ts[cg * 16 + u * 4 + 0][r] = (f16)v.x;
            Ts[cg * 16 + u * 4 + 1][r] = (f16)v.y;
            Ts[cg * 16 + u * 4 + 2][r] = (f16)v.z;
            Ts[cg * 16 + u * 4 + 3][r] = (f16)v.w;
        }
        __syncthreads();
        int dr = tid >> 2, seg = tid & 3;
        f16* dst = ctxT + ((size_t)b * Dc + d0 + dr) * Lc + l0 + seg * 16;
        f16x8 o0, o1;
#pragma unroll
        for (int j = 0; j < 8; ++j) { o0[j] = Ts[dr][seg * 16 + j]; o1[j] = Ts[dr][seg * 16 + 8 + j]; }
        *(f16x8*)dst = o0;
        *(f16x8*)(dst + 8) = o1;
    } else if (bid < 432) {
        // mm -> f16, 8 elems/thread: 48 blocks
        int gid = (bid - 384) * 256 + tid;
        const float4* src = (const float4*)(mm + (size_t)gid * 8);
        float4 v0 = src[0], v1 = src[1];
        f16x8 o;
        o[0] = (f16)v0.x; o[1] = (f16)v0.y; o[2] = (f16)v0.z; o[3] = (f16)v0.w;
        o[4] = (f16)v1.x; o[5] = (f16)v1.y; o[6] = (f16)v1.z; o[7] = (f16)v1.w;
        ((f16x8*)mmH)[gid] = o;
    } else if (bid < 560) {
        // em_tok: 128 blocks, one per (b,e)
        int be = bid - 432; int b = be / Ec;
        if (tid < Mc) rowS[tid] = em[(size_t)be * Mc + tid];
        __syncthreads();
        float v0 = 0.f, v1 = 0.f;
        {
            const float* mb0 = mm + (size_t)b * Mc * Lc + tid;
            const float* mb1 = mm + (size_t)b * Mc * Lc + tid + 256;
            for (int m = 0; m < Mc; ++m) {
                v0 += rowS[m] * mb0[(size_t)m * Lc];
                v1 += rowS[m] * mb1[(size_t)m * Lc];
            }
        }
        red[tid] = v0 + v1;
        __syncthreads();
        for (int s = 128; s > 0; s >>= 1) { if (tid < s) red[tid] += red[tid + s]; __syncthreads(); }
        if (tid == 0) inv = 1.f / (red[0] + MINV);
        __syncthreads();
        emtH[(size_t)be * Lc + tid] = (f16)(v0 * inv);
        emtH[(size_t)be * Lc + tid + 256] = (f16)(v1 * inv);
    } else if (bid < 584) {
        // tmpML zero: 24 blocks
        int base = ((bid - 560) * 256 + tid) * 4;
        float4 z = make_float4(0.f, 0.f, 0.f, 0.f);
        float4* t4 = (float4*)tmpML;
#pragma unroll
        for (int u = 0; u < 4; ++u) t4[base + u] = z;
    } else {
        // out bias init: 194 blocks * 256 threads * 4 = 198656 = 2048*97 exactly
        int base = ((bid - 584) * 256 + tid) * 4;
#pragma unroll
        for (int u = 0; u < 4; ++u) {
            int idx = base + u;
            out[idx] = cb[idx % Rc];
        }
    }
}

// ---------------- K2 merged: attpass 64-col (0..383) + mention MFMA (384..431)
//                 + weight cvt (432..2479) + clasW->Wp swizzle (2480..5551). ----------------
__global__ __launch_bounds__(256) void k_att_mention(const f16* __restrict__ mmH,
                                                     const f16* __restrict__ emtH,
                                                     const float* __restrict__ att,
                                                     float* __restrict__ tmpML,
                                                     float* __restrict__ eat,
                                                     const f16* __restrict__ ctxT,
                                                     float* __restrict__ mention,
                                                     const float* __restrict__ hW, const float* __restrict__ tW,
                                                     const float* __restrict__ hcW, const float* __restrict__ tcW,
                                                     f16* __restrict__ hWb, f16* __restrict__ tWb,
                                                     f16* __restrict__ hcWb, f16* __restrict__ tcWb,
                                                     const float* __restrict__ clasW, f16* __restrict__ Wp) {
    __shared__ __align__(16) char smem[32768];
    int bid = blockIdx.x;
    int tid = threadIdx.x;
    int w = tid >> 6, lane = tid & 63;
    if (bid < 384) {
        // ---- attpass ----
        f16* Ss   = (f16*)smem;            // 96*64
        f16* attS = (f16*)(smem + 12288);  // 64*64
        int mt = bid & 7; int bh = bid >> 3;
        int b = bh / Hc, h = bh % Hc;
        int m0 = mt * 64;
        int n_l = lane & 31, kg = lane >> 5;

        const float* ab = att + (size_t)bh * Lc * Lc + m0;
        int mRow = tid & 63, lg = tid >> 6;
        float pre[16];
#pragma unroll
        for (int q = 0; q < 16; ++q) pre[q] = ab[(size_t)(lg * 16 + q) * Lc + mRow];

        f32x16 acc[2];
#pragma unroll
        for (int nt = 0; nt < 2; ++nt)
#pragma unroll
            for (int i = 0; i < 16; ++i) acc[nt][i] = 0.f;

        for (int kc = 0; kc < 8; ++kc) {
            __syncthreads();
#pragma unroll
            for (int half = 0; half < 2; ++half) {
                int cc = lg * 2 + half;
                f16x8 v;
#pragma unroll
                for (int jj = 0; jj < 8; ++jj) v[jj] = (f16)pre[half * 8 + jj];
                ((f16x8*)attS)[mRow * 8 + (cc ^ (mRow & 7))] = v;
            }
#pragma unroll
            for (int k = 0; k < 3; ++k) {
                int idx = tid + k * 256;
                int row = idx >> 3, cc = idx & 7;
                f16x8 v;
                if (row < Mc) {
                    v = *(const f16x8*)(mmH + ((size_t)b * Mc + row) * Lc + kc * 64 + cc * 8);
                } else if (row < 80) {
                    v = *(const f16x8*)(emtH + ((size_t)b * Ec + row - Mc) * Lc + kc * 64 + cc * 8);
                } else {
#pragma unroll
                    for (int j = 0; j < 8; ++j) v[j] = (f16)0.f;
                }
                ((f16x8*)Ss)[row * 8 + (cc ^ (row & 7))] = v;
            }
            if (kc < 7) {
#pragma unroll
                for (int q = 0; q < 16; ++q)
                    pre[q] = ab[(size_t)((kc + 1) * 64 + lg * 16 + q) * Lc + mRow];
            }
            __syncthreads();
            if (w < 3) {
                int arow = w * 32 + n_l;
#pragma unroll
                for (int kk = 0; kk < 4; ++kk) {
                    int cc = kk * 2 + kg;
                    f16x8 a = ((const f16x8*)Ss)[arow * 8 + (cc ^ (arow & 7))];
#pragma unroll
                    for (int nt = 0; nt < 2; ++nt) {
                        int bcol = nt * 32 + n_l;
                        f16x8 bb = ((const f16x8*)attS)[bcol * 8 + (cc ^ (bcol & 7))];
                        acc[nt] = __builtin_amdgcn_mfma_f32_32x32x16_f16(a, bb, acc[nt], 0, 0, 0);
                    }
                }
            }
        }
        if (w < 3) {
#pragma unroll
            for (int nt = 0; nt < 2; ++nt)
#pragma unroll
                for (int reg = 0; reg < 16; ++reg) {
                    int row = (reg & 3) + 8 * (reg >> 2) + 4 * kg;
                    int rr = w * 32 + row;
                    int col = m0 + nt * 32 + n_l;
                    if (rr < Mc) {
                        atomicAdd(&tmpML[((size_t)b * Mc + rr) * Lc + col], acc[nt][reg]);
                    } else if (rr < 80) {
                        eat[(((size_t)b * Hc + h) * Ec + (rr - Mc)) * Lc + col] = acc[nt][reg];
                    }
                }
        }
    } else if (bid < 432) {
        // ---- mention = mm @ ctx ----
        f16* As = (f16*)smem;             // 2 * 64*64
        f16* Bs = (f16*)(smem + 16384);   // 2 * 64*64
        int id = bid - 384;               // b*12+dt
        int dt = id % 12; int b = id / 12;
        int d0 = dt * 64;
        int w_m = w & 1, w_n = w >> 1;
        int m_l = lane & 31, kg = lane >> 5;
        int r0 = tid >> 3, cc0 = tid & 7;
        int r1 = r0 + 32;
        int mr0 = (r0 < Mc) ? r0 : r0 - Mc;
        int mr1 = (r1 < Mc) ? r1 : r1 - Mc;
        f16x8 ar0, ar1, br0, br1;
        auto loadt = [&](int it) {
            int k0 = it * 64;
            ar0 = *(const f16x8*)(mmH + ((size_t)b * Mc + mr0) * Lc + k0 + cc0 * 8);
            ar1 = *(const f16x8*)(mmH + ((size_t)b * Mc + mr1) * Lc + k0 + cc0 * 8);
            br0 = *(const f16x8*)(ctxT + ((size_t)b * Dc + d0 + r0) * Lc + k0 + cc0 * 8);
            br1 = *(const f16x8*)(ctxT + ((size_t)b * Dc + d0 + r1) * Lc + k0 + cc0 * 8);
        };
        auto writet = [&](int p) {
            ((f16x8*)(As + p * 4096))[r0 * 8 + (cc0 ^ (r0 & 7))] = ar0;
            ((f16x8*)(As + p * 4096))[r1 * 8 + (cc0 ^ (r1 & 7))] = ar1;
            ((f16x8*)(Bs + p * 4096))[r0 * 8 + (cc0 ^ (r0 & 7))] = br0;
            ((f16x8*)(Bs + p * 4096))[r1 * 8 + (cc0 ^ (r1 & 7))] = br1;
        };
        loadt(0); writet(0); loadt(1);
        f32x16 acc;
#pragma unroll
        for (int i = 0; i < 16; ++i) acc[i] = 0.f;
        int ar = w_m * 32 + m_l;
        int br = w_n * 32 + m_l;
        for (int it = 0; it < 8; ++it) {
            int p = it & 1;
            __syncthreads();
            if (it < 7) writet(p ^ 1);
            if (it < 6) loadt(it + 2);
#pragma unroll
            for (int s = 0; s < 4; ++s) {
                int ck = s * 2 + kg;
                f16x8 a = ((const f16x8*)(As + p * 4096))[ar * 8 + (ck ^ (ar & 7))];
                f16x8 bv = ((const f16x8*)(Bs + p * 4096))[br * 8 + (ck ^ (br & 7))];
                acc = __builtin_amdgcn_mfma_f32_32x32x16_f16(a, bv, acc, 0, 0, 0);
            }
        }
#pragma unroll
        for (int reg = 0; reg < 16; ++reg) {
            int row = (reg & 3) + 8 * (reg >> 2) + 4 * kg;
            int m = w_m * 32 + row;
            if (m < Mc) mention[((size_t)b * Mc + m) * Dc + d0 + w_n * 32 + m_l] = acc[reg];
        }
    } else if (bid < 2480) {
        // ---- weight cvt, float4-vectorized ----
        const int Q = 147456;   // DD/4
        int i = (bid - 432) * 256 + tid;
        int stride = 2048 * 256;
        for (; i < 4 * Q; i += stride) {
            int sel = i / Q, j = i % Q;
            const float* s = (sel == 0) ? hW : (sel == 1) ? tW : (sel == 2) ? hcW : tcW;
            f16* d = (sel == 0) ? hWb : (sel == 1) ? tWb : (sel == 2) ? hcWb : tcWb;
            float4 v = ((const float4*)s)[j];
            f16x4 o;
            o[0] = (f16)v.x; o[1] = (f16)v.y; o[2] = (f16)v.z; o[3] = (f16)v.w;
            ((f16x4*)d)[j] = o;
        }
    } else {
        // ---- clasW -> Wp swizzle, LDS-staged ----
        f16 (*LsW)[72] = (f16 (*)[72])smem;
        int id2 = bid - 2480;
        int c = id2 >> 2, rt = id2 & 3;
        for (int idx = tid; idx < 512; idx += 256) {
            int row = idx >> 4, q = idx & 15;
            int r = rt * 32 + row;
            f16x4 o;
            if (r < Rc) {
                float4 v = *(const float4*)(clasW + (size_t)r * (Dc * 64) + c * 64 + q * 4);
                o[0] = (f16)v.x; o[1] = (f16)v.y; o[2] = (f16)v.z; o[3] = (f16)v.w;
            } else {
                o[0] = (f16)0.f; o[1] = (f16)0.f; o[2] = (f16)0.f; o[3] = (f16)0.f;
            }
            *(f16x4*)(&LsW[row][q * 4]) = o;
        }
        __syncthreads();
        int s = tid >> 6;
        int n_l = lane & 31, kg = lane >> 5;
        f16x8 outv = *(const f16x8*)(&LsW[n_l][s * 16 + kg * 8]);
        ((f16x8*)Wp)[(size_t)(c * 16 + s * 4 + rt) * 64 + lane] = outv;
    }
}

// ---------------- K3a: mention_att, one wave per output element (fp32) ----------------
__global__ __launch_bounds__(256) void k_ma(const float* __restrict__ tmp,
                                            const float* __restrict__ mm,
                                            float* __restrict__ maS) {
    int wv = threadIdx.x >> 6, lane = threadIdx.x & 63;
    int gid = blockIdx.x * 4 + wv;              // < Bc*48*48 = 9216
    int m2 = gid % 48;
    int m  = (gid / 48) % 48;
    int b  = gid / (48 * 48);
    const float4* t = (const float4*)(tmp + ((size_t)b * Mc + m)  * Lc);
    const float4* r = (const float4*)(mm  + ((size_t)b * Mc + m2) * Lc);
    float4 a0 = t[lane],      b0 = r[lane];
    float4 a1 = t[lane + 64], b1 = r[lane + 64];
    float acc = a0.x * b0.x + a0.y * b0.y + a0.z * b0.z + a0.w * b0.w
              + a1.x * b1.x + a1.y * b1.y + a1.z * b1.z + a1.w * b1.w;
#pragma unroll
    for (int off = 1; off < 64; off <<= 1) acc += __shfl_xor(acc, off);
    if (lane == 0) maS[gid] = acc;
}

// ---------------- K5a: per-bp pair prep (1 wave per bp), entity_att rows computed inline ----------------
__global__ __launch_bounds__(256) void k_pair(const int* __restrict__ hts,
                                              const float* __restrict__ em,
                                              const float* __restrict__ maS,
                                              const float* __restrict__ eat,
                                              f16* __restrict__ hatN, f16* __restrict__ tatN,
                                              f16* __restrict__ caH) {
    int wv = threadIdx.x >> 6, lane = threadIdx.x & 63;
    int bp = blockIdx.x * 4 + wv;
    int b = bp >> 9;
    int hi = hts[bp * 2], ti = hts[bp * 2 + 1];
    float mask = (hi + ti != 0) ? 1.f : 0.f;
    float hat = 0.f, tat = 0.f;
    if (lane < Mc) {
        float hm = em[((size_t)(b * Ec + hi)) * Mc + lane];
        float tm = em[((size_t)(b * Ec + ti)) * Mc + lane];
        float eh = 0.f, et = 0.f;
        const float* maB = maS + (size_t)b * Mc * Mc;
        const float* emH = em + ((size_t)(b * Ec + hi)) * Mc;
        const float* emT = em + ((size_t)(b * Ec + ti)) * Mc;
#pragma unroll 8
        for (int m = 0; m < Mc; ++m) {
            float ms = maB[m * Mc + lane];
            eh += emH[m] * ms;
            et += emT[m] * ms;
        }
        hat = eh * tm * mask;
        tat = et * hm * mask;
    }
    float sh = hat, st = tat;
#pragma unroll
    for (int off = 1; off < 64; off <<= 1) { sh += __shfl_xor(sh, off); st += __shfl_xor(st, off); }
    float hnorm = 1.f / (sh + MINV);
    float tnorm = 1.f / (st + MINV);
    hatN[(size_t)bp * 64 + lane] = (f16)(hat * hnorm);
    tatN[(size_t)bp * 64 + lane] = (f16)(tat * tnorm);

    const float* base = eat + (size_t)b * Hc * Ec * Lc;
    float prod[8];
    float tot = 0.f;
#pragma unroll
    for (int j8 = 0; j8 < 8; ++j8) {
        int j = j8 * 64 + lane;
        float a = 0.f;
#pragma unroll
        for (int h = 0; h < Hc; ++h)
            a += base[((size_t)h * Ec + hi) * Lc + j] * base[((size_t)h * Ec + ti) * Lc + j];
        prod[j8] = a;
        tot += a;
    }
#pragma unroll
    for (int off = 1; off < 64; off <<= 1) tot += __shfl_xor(tot, off);
    float inv = 1.f / (tot + MINV);
#pragma unroll
    for (int j8 = 0; j8 < 8; ++j8)
        caH[(size_t)bp * Lc + j8 * 64 + lane] = (f16)(prod[j8] * inv);
}

// ---------------- K5b merged: ht MFMA (blocks 0..383) + ctxinfo MFMA (blocks 384..767) ----------------
__global__ __launch_bounds__(256) void k_htci(const f16* __restrict__ tatN, const f16* __restrict__ hatN,
                                              const float* __restrict__ mention,
                                              f16* __restrict__ hB, f16* __restrict__ tB,
                                              const int* __restrict__ hts,
                                              const f16* __restrict__ caH,
                                              const f16* __restrict__ ctxT,
                                              f16* __restrict__ ci) {
    __shared__ __align__(16) char smem[33024];
    int bid = blockIdx.x;
    int tid = threadIdx.x;
    int w = tid >> 6, lane = tid & 63;
    int w_m = w & 1, w_n = w >> 1;
    int m_l = lane & 31, kg = lane >> 5;
    if (bid < 384) {
        // ---- ht: h = tatN @ mention, t = hatN @ mention (K=64 single tile) ----
        f16* At = (f16*)smem;              // 64*64
        f16* Ah = (f16*)(smem + 8192);     // 64*64
        f16* Bs = (f16*)(smem + 16384);    // 64*64
        int m0 = (bid & 31) * 64;          // p base
        int b = m0 >> 9;
        int d0 = (bid >> 5) * 64;

        for (int i = tid; i < 512; i += 256) {
            int p = i >> 3, c = i & 7;
            ((f16x8*)At)[p * 8 + (c ^ (p & 7))] = *(const f16x8*)(tatN + (size_t)(m0 + p) * 64 + c * 8);
            ((f16x8*)Ah)[p * 8 + (c ^ (p & 7))] = *(const f16x8*)(hatN + (size_t)(m0 + p) * 64 + c * 8);
        }
        for (int i = tid; i < 512; i += 256) {
            f16x8 z;
#pragma unroll
            for (int j = 0; j < 8; ++j) z[j] = (f16)0.f;
            ((f16x8*)Bs)[i] = z;
        }
        __syncthreads();
        if (tid < 192) {
            int m = tid >> 2, q = tid & 3;
            const float4* src = (const float4*)(mention + ((size_t)b * Mc + m) * Dc + d0 + q * 16);
#pragma unroll
            for (int u = 0; u < 4; ++u) {
                float4 v = src[u];
                int dl = q * 16 + u * 4;
#pragma unroll
                for (int x = 0; x < 4; ++x) {
                    float vv = (x == 0) ? v.x : (x == 1) ? v.y : (x == 2) ? v.z : v.w;
                    int d = dl + x;
                    Bs[(d * 8 + ((m >> 3) ^ (d & 7))) * 8 + (m & 7)] = (f16)vv;
                }
            }
        }
        __syncthreads();

        f32x16 acch, acct;
#pragma unroll
        for (int i = 0; i < 16; ++i) { acch[i] = 0.f; acct[i] = 0.f; }
        int ar = w_m * 32 + m_l;
        int br = w_n * 32 + m_l;
#pragma unroll
        for (int s = 0; s < 4; ++s) {
            int ck = s * 2 + kg;
            f16x8 at_ = ((const f16x8*)At)[ar * 8 + (ck ^ (ar & 7))];
            f16x8 ah_ = ((const f16x8*)Ah)[ar * 8 + (ck ^ (ar & 7))];
            f16x8 bv = ((const f16x8*)Bs)[br * 8 + (ck ^ (br & 7))];
            acch = __builtin_amdgcn_mfma_f32_32x32x16_f16(at_, bv, acch, 0, 0, 0);
            acct = __builtin_amdgcn_mfma_f32_32x32x16_f16(ah_, bv, acct, 0, 0, 0);
        }
#pragma unroll
        for (int reg = 0; reg < 16; ++reg) {
            int row = (reg & 3) + 8 * (reg >> 2) + 4 * kg;
            int p = m0 + w_m * 32 + row;
            int d = d0 + w_n * 32 + m_l;
            hB[(size_t)p * Dc + d] = (f16)acch[reg];
            tB[(size_t)p * Dc + d] = (f16)acct[reg];
        }
    } else {
        // ---- ctxinfo = ca @ ctx^T, masked ----
        f16* As = (f16*)smem;              // 2 * 64*64
        f16* Bs = (f16*)(smem + 16384);    // 2 * 64*64
        float* maskS = (float*)(smem + 32768);
        int id = bid - 384;                // ((b*8+pt)*12+dt)
        int dt = id % 12; int pt = (id / 12) % 8; int b = id / 96;
        int p0 = pt * 64, d0 = dt * 64;
        int r0 = tid >> 3, cc0 = tid & 7;
        int r1 = r0 + 32;
        if (tid < 64) {
            int bp = b * Pc + p0 + tid;
            maskS[tid] = (hts[bp * 2] + hts[bp * 2 + 1] != 0) ? 1.f : 0.f;
        }
        f16x8 ar0, ar1, br0, br1;
        auto loadt = [&](int it) {
            int k0 = it * 64;
            ar0 = *(const f16x8*)(caH + (size_t)(b * Pc + p0 + r0) * Lc + k0 + cc0 * 8);
            ar1 = *(const f16x8*)(caH + (size_t)(b * Pc + p0 + r1) * Lc + k0 + cc0 * 8);
            br0 = *(const f16x8*)(ctxT + (size_t)(b * Dc + d0 + r0) * Lc + k0 + cc0 * 8);
            br1 = *(const f16x8*)(ctxT + (size_t)(b * Dc + d0 + r1) * Lc + k0 + cc0 * 8);
        };
        auto writet = [&](int p) {
            ((f16x8*)(As + p * 4096))[r0 * 8 + (cc0 ^ (r0 & 7))] = ar0;
            ((f16x8*)(As + p * 4096))[r1 * 8 + (cc0 ^ (r1 & 7))] = ar1;
            ((f16x8*)(Bs + p * 4096))[r0 * 8 + (cc0 ^ (r0 & 7))] = br0;
            ((f16x8*)(Bs + p * 4096))[r1 * 8 + (cc0 ^ (r1 & 7))] = br1;
        };
        loadt(0); writet(0); loadt(1);
        f32x16 acc;
#pragma unroll
        for (int i = 0; i < 16; ++i) acc[i] = 0.f;
        int ar = w_m * 32 + m_l;
        int br = w_n * 32 + m_l;
        for (int it = 0; it < 8; ++it) {
            int p = it & 1;
            __syncthreads();
            if (it < 7) writet(p ^ 1);
            if (it < 6) loadt(it + 2);
#pragma unroll
            for (int s = 0; s < 4; ++s) {
                int ck = s * 2 + kg;
                f16x8 a = ((const f16x8*)(As + p * 4096))[ar * 8 + (ck ^ (ar & 7))];
                f16x8 bv = ((const f16x8*)(Bs + p * 4096))[br * 8 + (ck ^ (br & 7))];
                acc = __builtin_amdgcn_mfma_f32_32x32x16_f16(a, bv, acc, 0, 0, 0);
            }
        }
#pragma unroll
        for (int reg = 0; reg < 16; ++reg) {
            int row = (reg & 3) + 8 * (reg >> 2) + 4 * kg;
            int p = p0 + w_m * 32 + row;
            int d = d0 + w_n * 32 + m_l;
            ci[(size_t)(b * Pc + p) * Dc + d] = (f16)(acc[reg] * maskS[w_m * 32 + row]);
        }
    }
}

// ---------------- K10: MFMA proj merged (z=2), f16, global_load_lds staging ----------------
__global__ __launch_bounds__(256) void k_proj_mfma(const f16* __restrict__ Xh, const f16* __restrict__ Wh,
                                                   const float* __restrict__ bh,
                                                   const f16* __restrict__ Xt, const f16* __restrict__ Wt,
                                                   const float* __restrict__ bt,
                                                   const f16* __restrict__ Xc, const f16* __restrict__ Whc,
                                                   const float* __restrict__ bhc,
                                                   const f16* __restrict__ Wtc, const float* __restrict__ btc,
                                                   f16* __restrict__ outh, f16* __restrict__ outt) {
    __shared__ __align__(16) f16 Xs[2][64 * 64];
    __shared__ __align__(16) f16 Ws[2][64 * 64];
    int z = blockIdx.z;
    const f16* X1 = z ? Xt : Xh;
    const f16* W1 = z ? Wt : Wh;
    const float* b1 = z ? bt : bh;
    const f16* W2 = z ? Wtc : Whc;
    const float* b2 = z ? btc : bhc;
    f16* outp = z ? outt : outh;
    int m0 = blockIdx.x * 64, n0 = blockIdx.y * 64;
    int tid = threadIdx.x;
    int w = tid >> 6, lane = tid & 63;
    int w_m = w & 1, w_n = w >> 1;
    int m_l = lane & 31, kg = lane >> 5;
    const f16* Xarr[2] = {X1, Xc};
    const f16* Warr[2] = {W1, W2};

    auto stage = [&](int p, int it) {
        int src = it / 12; int k0 = (it % 12) * 64;
        const f16* X = Xarr[src]; const f16* W = Warr[src];
#pragma unroll
        for (int g = 0; g < 2; ++g) {
            int s = g * 256 + w * 64 + lane;
            int r = s >> 3, c = (s & 7) ^ (r & 7);
            __builtin_amdgcn_global_load_lds(
                (const __attribute__((address_space(1))) void*)(X + (size_t)(m0 + r) * Dc + k0 + c * 8),
                (__attribute__((address_space(3))) void*)(&Xs[p][(g * 256 + w * 64) * 8]),
                16, 0, 0);
            __builtin_amdgcn_global_load_lds(
                (const __attribute__((address_space(1))) void*)(W + (size_t)(n0 + r) * Dc + k0 + c * 8),
                (__attribute__((address_space(3))) void*)(&Ws[p][(g * 256 + w * 64) * 8]),
                16, 0, 0);
        }
    };

    stage(0, 0);
    f32x16 acc;
#pragma unroll
    for (int i = 0; i < 16; ++i) acc[i] = 0.f;
    int ar = w_m * 32 + m_l;
    int br = w_n * 32 + m_l;
    for (int it = 0; it < 24; ++it) {
        int p = it & 1;
        __syncthreads();
        if (it < 23) stage(p ^ 1, it + 1);
#pragma unroll
        for (int s = 0; s < 4; ++s) {
            int ck = s * 2 + kg;
            f16x8 a = ((const f16x8*)Xs[p])[ar * 8 + (ck ^ (ar & 7))];
            f16x8 b = ((const f16x8*)Ws[p])[br * 8 + (ck ^ (br & 7))];
            acc = __builtin_amdgcn_mfma_f32_32x32x16_f16(a, b, acc, 0, 0, 0);
        }
    }
#pragma unroll
    for (int reg = 0; reg < 16; ++reg) {
        int row = (reg & 3) + 8 * (reg >> 2) + 4 * kg;
        int m = m0 + w_m * 32 + row;
        int n = n0 + w_n * 32 + m_l;
        float v = tanhf(acc[reg] + b1[n] + b2[n]);
        outp[(size_t)m * Dc + n] = (f16)v;
    }
}

// ---------------- K11: group bilinear. tile=128 bp, slice=64 cc (one n-group), rt per block.
// f32 atomicAdd directly into out (pre-initialized with bias). No partial buffer, no k_reduce. ----------------
__global__ __launch_bounds__(256, 3) void k_bilin(const f16* __restrict__ hF, const f16* __restrict__ tF,
                                                  const f16* __restrict__ Wp, float* __restrict__ out) {
    __shared__ __align__(16) f16 tS[128 * 64];   // reused as f32 combine buffer after the cc loop
    __shared__ f16 hS[128 * 65];
    int id = blockIdx.x;
    int rt = id & 3;               // r-tile 0..3
    int st = id >> 2;
    int slice = st % NSLICE;       // 12 slices of 64 cc = one n-group each
    int tile = st / NSLICE;        // 16 tiles of 128 bp
    int bp0 = tile * 128;
    int c0 = slice * 64;
    int n = slice;
    int tid = threadIdx.x;
    int w = tid >> 6, lane = tid & 63;
    int w_m = w & 1, w_half = w >> 1;   // cc half (0: cc 0..31, 1: cc 32..63)
    int m_l = lane & 31, kg = lane >> 5;

    for (int idx = tid; idx < 128 * 8; idx += 256) {
        int bp = idx >> 3, seg = idx & 7;
        f16x8 hv = *(const f16x8*)(hF + (size_t)(bp0 + bp) * Dc + c0 + seg * 8);
#pragma unroll
        for (int j = 0; j < 8; ++j) hS[bp * 65 + seg * 8 + j] = hv[j];
    }
    for (int idx = tid; idx < 128 * 8; idx += 256) {
        int bp = idx >> 3, cc = idx & 7;
        f16x8 tv = *(const f16x8*)(tF + (size_t)(bp0 + bp) * Dc + n * 64 + cc * 8);
        ((f16x8*)tS)[bp * 8 + (cc ^ (bp & 7))] = tv;
    }
    __syncthreads();

    int rowA = w_m * 64 + m_l;
    int rowB = rowA + 32;

    f16x8 tvA[4], tvB[4];
#pragma unroll
    for (int s = 0; s < 4; ++s) {
        int ck = s * 2 + kg;
        tvA[s] = ((const f16x8*)tS)[rowA * 8 + (ck ^ (rowA & 7))];
        tvB[s] = ((const f16x8*)tS)[rowB * 8 + (ck ^ (rowB & 7))];
    }

    f32x16 acc[2];
#pragma unroll
    for (int mt = 0; mt < 2; ++mt)
#pragma unroll
        for (int i = 0; i < 16; ++i) acc[mt][i] = 0.f;

    const f16x8* wpb = (const f16x8*)Wp + ((size_t)(c0 + w_half * 32) * 16 + rt) * 64 + lane;
    int hbase = w_half * 32;
    f16x8 BfA[4], BfB[4];
#pragma unroll
    for (int s = 0; s < 4; ++s) BfA[s] = wpb[s * 256];

    for (int io = 0; io < 32; io += 2) {
#pragma unroll
        for (int s = 0; s < 4; ++s) BfB[s] = wpb[(io + 1) * 1024 + s * 256];
        {
            f16 hv0 = hS[rowA * 65 + hbase + io];
            f16 hv1 = hS[rowB * 65 + hbase + io];
#pragma unroll
            for (int s = 0; s < 4; ++s) {
                f16x8 a0 = tvA[s] * hv0;
                f16x8 a1 = tvB[s] * hv1;
                acc[0] = __builtin_amdgcn_mfma_f32_32x32x16_f16(a0, BfA[s], acc[0], 0, 0, 0);
                acc[1] = __builtin_amdgcn_mfma_f32_32x32x16_f16(a1, BfA[s], acc[1], 0, 0, 0);
            }
        }
        if (io + 2 < 32) {
#pragma unroll
            for (int s = 0; s < 4; ++s) BfA[s] = wpb[(io + 2) * 1024 + s * 256];
        }
        {
            f16 hv0 = hS[rowA * 65 + hbase + io + 1];
            f16 hv1 = hS[rowB * 65 + hbase + io + 1];
#pragma unroll
            for (int s = 0; s < 4; ++s) {
                f16x8 a0 = tvA[s] * hv0;
                f16x8 a1 = tvB[s] * hv1;
                acc[0] = __builtin_amdgcn_mfma_f32_32x32x16_f16(a0, BfB[s], acc[0], 0, 0, 0);
                acc[1] = __builtin_amdgcn_mfma_f32_32x32x16_f16(a1, BfB[s], acc[1], 0, 0, 0);
            }
        }
    }

    // combine cc-halves in f32 via LDS (tS reused), then atomicAdd f32 into out
    float* comb = (float*)tS;    // 4*16*64 f32 = 16 KB
    __syncthreads();
    if (w_half == 1) {
#pragma unroll
        for (int mt = 0; mt < 2; ++mt)
#pragma unroll
            for (int reg = 0; reg < 16; ++reg)
                comb[((w_m * 2 + mt) * 16 + reg) * 64 + lane] = acc[mt][reg];
    }
    __syncthreads();
    if (w_half == 0) {
        int r = rt * 32 + m_l;
        if (r < Rc) {
#pragma unroll
            for (int mt = 0; mt < 2; ++mt)
#pragma unroll
                for (int reg = 0; reg < 16; ++reg) {
                    float v = acc[mt][reg] + comb[((w_m * 2 + mt) * 16 + reg) * 64 + lane];
                    int row = (reg & 3) + 8 * (reg >> 2) + 4 * kg;
                    int bp = bp0 + w_m * 64 + mt * 32 + row;
                    atomicAdd(&out[(size_t)bp * Rc + r], v);
                }
        }
    }
}

extern "C" void kernel_launch(void* const* d_in, const int* in_sizes, int n_in,
                              void* d_out, int out_size, void* d_ws, size_t ws_size,
                              hipStream_t stream) {
    const float* context   = (const float*)d_in[0];
    const float* attention = (const float*)d_in[1];
    const float* mm        = (const float*)d_in[2];
    const float* em        = (const float*)d_in[3];
    const int*   hts       = (const int*)d_in[4];
    const float* hW        = (const float*)d_in[5];
    const float* hb        = (const float*)d_in[6];
    const float* tW        = (const float*)d_in[7];
    const float* tb        = (const float*)d_in[8];
    const float* hcW       = (const float*)d_in[9];
    const float* hcb       = (const float*)d_in[10];
    const float* tcW       = (const float*)d_in[11];
    const float* tcb       = (const float*)d_in[12];
    const float* clasW     = (const float*)d_in[13];
    const float* clasb     = (const float*)d_in[14];
    float* out = (float*)d_out;

    char* wsb = (char*)d_ws;
    auto alloc = [&](size_t bytes) { char* p = wsb; wsb += (bytes + 255) & ~(size_t)255; return p; };
    float* mention     = (float*)alloc((size_t)Bc * Mc * Dc * 4);
    float* tmpML       = (float*)alloc((size_t)Bc * Mc * Lc * 4);
    float* ent_att     = (float*)alloc((size_t)Bc * Hc * Ec * Lc * 4);
    float* maS         = (float*)alloc((size_t)Bc * Mc * Mc * 4);
    f16* em_tok  = (f16*)alloc((size_t)Bc * Ec * Lc * 2);
    f16* ctx_att = (f16*)alloc((size_t)Bc * Pc * Lc * 2);
    f16* mmH     = (f16*)alloc((size_t)Bc * Mc * Lc * 2);
    f16* hatN    = (f16*)alloc((size_t)Bc * Pc * 64 * 2);
    f16* tatN    = (f16*)alloc((size_t)Bc * Pc * 64 * 2);
    f16* h_buf   = (f16*)alloc((size_t)Bc * Pc * Dc * 2);
    f16* t_buf   = (f16*)alloc((size_t)Bc * Pc * Dc * 2);
    f16* ctxinfo = (f16*)alloc((size_t)Bc * Pc * Dc * 2);
    f16* h_fin   = (f16*)alloc((size_t)Bc * Pc * Dc * 2);
    f16* t_fin   = (f16*)alloc((size_t)Bc * Pc * Dc * 2);
    f16* hWb     = (f16*)alloc((size_t)Dc * Dc * 2);
    f16* tWb     = (f16*)alloc((size_t)Dc * Dc * 2);
    f16* hcWb    = (f16*)alloc((size_t)Dc * Dc * 2);
    f16* tcWb    = (f16*)alloc((size_t)Dc * Dc * 2);
    f16* ctxT    = (f16*)alloc((size_t)Bc * Dc * Lc * 2);
    f16* Wp      = (f16*)alloc((size_t)768 * 16 * 64 * 8 * 2);

    k_prep<<<dim3(778), dim3(256), 0, stream>>>(context, ctxT, mm, mmH, em, em_tok, tmpML, clasb, out);
    k_att_mention<<<dim3(5552), dim3(256), 0, stream>>>(mmH, em_tok, attention, tmpML, ent_att,
                                                        ctxT, mention,
                                                        hW, tW, hcW, tcW, hWb, tWb, hcWb, tcWb,
                                                        clasW, Wp);
    k_ma<<<dim3(Bc * Mc * Mc / 4), dim3(256), 0, stream>>>(tmpML, mm, maS);
    k_pair<<<dim3(Bc * Pc / 4), dim3(256), 0, stream>>>(hts, em, maS, ent_att, hatN, tatN, ctx_att);
    k_htci<<<dim3(768), dim3(256), 0, stream>>>(tatN, hatN, mention, h_buf, t_buf,
                                                hts, ctx_att, ctxT, ctxinfo);
    k_proj_mfma<<<dim3(32, 12, 2), dim3(256), 0, stream>>>(h_buf, hWb, hb, t_buf, tWb, tb,
                                                           ctxinfo, hcWb, hcb, tcWb, tcb, h_fin, t_fin);
    k_bilin<<<dim3(16 * NSLICE * 4), dim3(256), 0, stream>>>(h_fin, t_fin, Wp, out);
}